// Round 2
// baseline (7695.596 us; speedup 1.0000x reference)
//
#include <hip/hip_runtime.h>
#include <hip/hip_bf16.h>
#include <math.h>

#define B_   2
#define S_   2048
#define D_   4096
#define HQ_  32
#define HK_  8
#define HD_  128
#define REP_ 4
#define M_   (B_*S_)   // 4096 rows of x

// ---------------------------------------------------------------------------
// Tiled fp32 GEMM: C[M][N] = A[M][K] @ B[K][N], all row-major.
// 128x128 tile, BK=16, 256 threads, 8x8 micro-tile per thread.
// A staged transposed [k][m] (pad 132), B staged [k][n] (pad 132).
// ---------------------------------------------------------------------------
#define GT  128
#define GBK 16

__global__ __launch_bounds__(256)
void gemm_f32_kernel(const float* __restrict__ A, const float* __restrict__ Bm,
                     float* __restrict__ C, int M, int N, int K) {
    __shared__ float As[GBK][132];   // [k][m]
    __shared__ float Bs[GBK][132];   // [k][n]

    const int tid  = threadIdx.x;
    const int row0 = blockIdx.y * GT;
    const int col0 = blockIdx.x * GT;
    const int tx = tid & 15;   // cols tx*4 .. +3 and 64+tx*4 .. +3
    const int ty = tid >> 4;   // rows ty*8 .. +7

    float acc[8][8];
#pragma unroll
    for (int i = 0; i < 8; ++i)
#pragma unroll
        for (int j = 0; j < 8; ++j) acc[i][j] = 0.f;

    for (int k0 = 0; k0 < K; k0 += GBK) {
        float4 a[2], b[2];
#pragma unroll
        for (int t = 0; t < 2; ++t) {
            int f  = t * 256 + tid;
            int ar = f >> 2, ac = (f & 3) << 2;        // A: 128 rows x 16 cols
            a[t] = *reinterpret_cast<const float4*>(&A[(size_t)(row0 + ar) * K + k0 + ac]);
            int br = f >> 5, bc = (f & 31) << 2;       // B: 16 rows x 128 cols
            b[t] = *reinterpret_cast<const float4*>(&Bm[(size_t)(k0 + br) * N + col0 + bc]);
        }
        __syncthreads();   // previous iteration's LDS reads done
#pragma unroll
        for (int t = 0; t < 2; ++t) {
            int f  = t * 256 + tid;
            int ar = f >> 2, ac = (f & 3) << 2;
            As[ac + 0][ar] = a[t].x;
            As[ac + 1][ar] = a[t].y;
            As[ac + 2][ar] = a[t].z;
            As[ac + 3][ar] = a[t].w;
            int br = f >> 5, bc = (f & 31) << 2;
            *reinterpret_cast<float4*>(&Bs[br][bc]) = b[t];
        }
        __syncthreads();
#pragma unroll
        for (int kk = 0; kk < GBK; ++kk) {
            float4 a0 = *reinterpret_cast<const float4*>(&As[kk][ty * 8]);
            float4 a1 = *reinterpret_cast<const float4*>(&As[kk][ty * 8 + 4]);
            float4 b0 = *reinterpret_cast<const float4*>(&Bs[kk][tx * 4]);
            float4 b1 = *reinterpret_cast<const float4*>(&Bs[kk][tx * 4 + 64]);
            float av[8] = {a0.x, a0.y, a0.z, a0.w, a1.x, a1.y, a1.z, a1.w};
            float bv[8] = {b0.x, b0.y, b0.z, b0.w, b1.x, b1.y, b1.z, b1.w};
#pragma unroll
            for (int i = 0; i < 8; ++i)
#pragma unroll
                for (int j = 0; j < 8; ++j) acc[i][j] += av[i] * bv[j];
        }
    }
#pragma unroll
    for (int i = 0; i < 8; ++i) {
        int r = row0 + ty * 8 + i;
        *reinterpret_cast<float4*>(&C[(size_t)r * N + col0 + tx * 4]) =
            make_float4(acc[i][0], acc[i][1], acc[i][2], acc[i][3]);
        *reinterpret_cast<float4*>(&C[(size_t)r * N + col0 + 64 + tx * 4]) =
            make_float4(acc[i][4], acc[i][5], acc[i][6], acc[i][7]);
    }
}

// ---------------------------------------------------------------------------
// RoPE, in place on [B*S][H*HD]. One thread per (even,odd) pair.
// ---------------------------------------------------------------------------
__global__ __launch_bounds__(256)
void rope_kernel(float* __restrict__ x, const float* __restrict__ ctab,
                 const float* __restrict__ stab, int H, int total) {
    int idx = blockIdx.x * 256 + threadIdx.x;
    if (idx >= total) return;
    int i  = idx & 63;
    int h  = (idx >> 6) % H;
    int bs = idx / (64 * H);
    int s  = bs & (S_ - 1);
    size_t off = ((size_t)bs * H + h) * HD_ + 2 * i;
    float2 v = *reinterpret_cast<float2*>(&x[off]);
    float c  = ctab[(s << 6) + i];
    float sn = stab[(s << 6) + i];
    float2 o;
    o.x = v.x * c - v.y * sn;
    o.y = v.x * sn + v.y * c;
    *reinterpret_cast<float2*>(&x[off]) = o;
}

// ---------------------------------------------------------------------------
// Flash-style fp32 attention.
// Grid: (S/64) * HQ * B blocks, 256 threads each.
// ---------------------------------------------------------------------------
#define QT 64
#define KT 64
#define AP 132   // Q/K/V LDS row stride (floats)
#define PP 68    // P LDS row stride

__global__ __launch_bounds__(256)
void attn_kernel(const float* __restrict__ xq, const float* __restrict__ xk,
                 const float* __restrict__ xv, float* __restrict__ out) {
    __shared__ float Qs[QT][AP];
    __shared__ float Ks[KT][AP];
    __shared__ float Vs[KT][AP];
    __shared__ float Ps[QT][PP];
    __shared__ float red[4][QT];
    __shared__ float mrow[QT], lrow[QT], crow[QT];

    const int tid = threadIdx.x;
    const int bid = blockIdx.x;
    const int qb  = bid & 31;          // S_/QT = 32
    const int h   = (bid >> 5) & 31;   // HQ
    const int b   = bid >> 10;
    const int g   = h >> 2;            // kv head = h / REP

    const float* Qg = xq + ((size_t)b * S_ + (size_t)qb * QT) * (HQ_ * HD_) + h * HD_;
    const float* Kg = xk + (size_t)b * S_ * (HK_ * HD_) + g * HD_;
    const float* Vg = xv + (size_t)b * S_ * (HK_ * HD_) + g * HD_;
    float*       Og = out + ((size_t)b * S_ + (size_t)qb * QT) * (HQ_ * HD_) + h * HD_;

    const int tx = tid & 15;
    const int ty = tid >> 4;

    for (int c = 0; c < 8; ++c) {
        int idx4 = c * 256 + tid;
        int r  = idx4 >> 5;
        int c4 = (idx4 & 31) << 2;
        *reinterpret_cast<float4*>(&Qs[r][c4]) =
            *reinterpret_cast<const float4*>(&Qg[(size_t)r * (HQ_ * HD_) + c4]);
    }
    if (tid < QT) { mrow[tid] = -INFINITY; lrow[tid] = 0.f; }

    float o_acc[4][8];
#pragma unroll
    for (int i = 0; i < 4; ++i)
#pragma unroll
        for (int j = 0; j < 8; ++j) o_acc[i][j] = 0.f;

    const float scale = 0.08838834764831845f;   // 1/sqrt(128)

    for (int kt = 0; kt < S_ / KT; ++kt) {
        __syncthreads();
        const float* Kt_ = Kg + (size_t)kt * KT * (HK_ * HD_);
        const float* Vt_ = Vg + (size_t)kt * KT * (HK_ * HD_);
        for (int c = 0; c < 8; ++c) {
            int idx4 = c * 256 + tid;
            int r  = idx4 >> 5;
            int c4 = (idx4 & 31) << 2;
            *reinterpret_cast<float4*>(&Ks[r][c4]) =
                *reinterpret_cast<const float4*>(&Kt_[(size_t)r * (HK_ * HD_) + c4]);
            *reinterpret_cast<float4*>(&Vs[r][c4]) =
                *reinterpret_cast<const float4*>(&Vt_[(size_t)r * (HK_ * HD_) + c4]);
        }
        __syncthreads();

        // ---- S = Q @ K^T ----
        float sreg[4][4] = {{0.f,0.f,0.f,0.f},{0.f,0.f,0.f,0.f},
                            {0.f,0.f,0.f,0.f},{0.f,0.f,0.f,0.f}};
#pragma unroll 8
        for (int d = 0; d < HD_; d += 4) {
            float4 q[4], k[4];
#pragma unroll
            for (int ii = 0; ii < 4; ++ii)
                q[ii] = *reinterpret_cast<const float4*>(&Qs[ty + 16 * ii][d]);
#pragma unroll
            for (int jj = 0; jj < 4; ++jj)
                k[jj] = *reinterpret_cast<const float4*>(&Ks[tx + 16 * jj][d]);
#pragma unroll
            for (int ii = 0; ii < 4; ++ii)
#pragma unroll
                for (int jj = 0; jj < 4; ++jj)
                    sreg[ii][jj] += q[ii].x * k[jj].x + q[ii].y * k[jj].y +
                                    q[ii].z * k[jj].z + q[ii].w * k[jj].w;
        }
#pragma unroll
        for (int ii = 0; ii < 4; ++ii)
#pragma unroll
            for (int jj = 0; jj < 4; ++jj)
                Ps[ty + 16 * ii][tx + 16 * jj] = sreg[ii][jj] * scale;
        __syncthreads();

        // ---- online softmax ----
        const int row = tid & 63;
        const int p   = tid >> 6;
        float lm = -INFINITY;
        for (int j = 0; j < 16; ++j) lm = fmaxf(lm, Ps[row][p * 16 + j]);
        red[p][row] = lm;
        __syncthreads();
        if (tid < QT) {
            float mt = fmaxf(fmaxf(red[0][tid], red[1][tid]),
                             fmaxf(red[2][tid], red[3][tid]));
            float mo = mrow[tid];
            float mn = fmaxf(mo, mt);
            mrow[tid] = mn;
            crow[tid] = __expf(mo - mn);
        }
        __syncthreads();
        float mn = mrow[row];
        float psum = 0.f;
        for (int j = 0; j < 16; ++j) {
            float e = __expf(Ps[row][p * 16 + j] - mn);
            Ps[row][p * 16 + j] = e;
            psum += e;
        }
        red[p][row] = psum;
        __syncthreads();
        if (tid < QT)
            lrow[tid] = lrow[tid] * crow[tid] +
                        red[0][tid] + red[1][tid] + red[2][tid] + red[3][tid];

        // ---- O = O*corr + P @ V ----
        float cr[4];
#pragma unroll
        for (int ii = 0; ii < 4; ++ii) cr[ii] = crow[ty + 16 * ii];
#pragma unroll
        for (int ii = 0; ii < 4; ++ii)
#pragma unroll
            for (int dd = 0; dd < 8; ++dd) o_acc[ii][dd] *= cr[ii];
#pragma unroll 4
        for (int t = 0; t < KT; ++t) {
            float pv[4];
#pragma unroll
            for (int ii = 0; ii < 4; ++ii) pv[ii] = Ps[ty + 16 * ii][t];
            float4 v0 = *reinterpret_cast<const float4*>(&Vs[t][tx * 8]);
            float4 v1 = *reinterpret_cast<const float4*>(&Vs[t][tx * 8 + 4]);
            float vv[8] = {v0.x, v0.y, v0.z, v0.w, v1.x, v1.y, v1.z, v1.w};
#pragma unroll
            for (int ii = 0; ii < 4; ++ii)
#pragma unroll
                for (int dd = 0; dd < 8; ++dd) o_acc[ii][dd] += pv[ii] * vv[dd];
        }
    }

    __syncthreads();
#pragma unroll
    for (int ii = 0; ii < 4; ++ii) {
        int r = ty + 16 * ii;
        float inv = 1.f / lrow[r];
        float4 o0 = make_float4(o_acc[ii][0] * inv, o_acc[ii][1] * inv,
                                o_acc[ii][2] * inv, o_acc[ii][3] * inv);
        float4 o1 = make_float4(o_acc[ii][4] * inv, o_acc[ii][5] * inv,
                                o_acc[ii][6] * inv, o_acc[ii][7] * inv);
        *reinterpret_cast<float4*>(&Og[(size_t)r * (HQ_ * HD_) + tx * 8])     = o0;
        *reinterpret_cast<float4*>(&Og[(size_t)r * (HQ_ * HD_) + tx * 8 + 4]) = o1;
    }
}

// ---------------------------------------------------------------------------
extern "C" void kernel_launch(void* const* d_in, const int* in_sizes, int n_in,
                              void* d_out, int out_size, void* d_ws, size_t ws_size,
                              hipStream_t stream) {
    const float* x    = (const float*)d_in[0];
    const float* wq   = (const float*)d_in[1];
    const float* wk   = (const float*)d_in[2];
    const float* wv   = (const float*)d_in[3];
    const float* wo   = (const float*)d_in[4];
    const float* fcos = (const float*)d_in[5];
    const float* fsin = (const float*)d_in[6];
    float* out = (float*)d_out;

    float* xq   = (float*)d_ws;                    // 4096 x 4096
    float* xk   = xq + (size_t)M_ * (HQ_ * HD_);   // 4096 x 1024
    float* xv   = xk + (size_t)M_ * (HK_ * HD_);   // 4096 x 1024
    float* attn = xv + (size_t)M_ * (HK_ * HD_);   // 4096 x 4096

    dim3 blk(256);

    gemm_f32_kernel<<<dim3((HQ_*HD_)/GT, M_/GT), blk, 0, stream>>>(x, wq, xq, M_, HQ_*HD_, D_);
    gemm_f32_kernel<<<dim3((HK_*HD_)/GT, M_/GT), blk, 0, stream>>>(x, wk, xk, M_, HK_*HD_, D_);
    gemm_f32_kernel<<<dim3((HK_*HD_)/GT, M_/GT), blk, 0, stream>>>(x, wv, xv, M_, HK_*HD_, D_);

    {
        int totq = B_ * S_ * HQ_ * (HD_ / 2);
        int totk = B_ * S_ * HK_ * (HD_ / 2);
        rope_kernel<<<(totq + 255) / 256, blk, 0, stream>>>(xq, fcos, fsin, HQ_, totq);
        rope_kernel<<<(totk + 255) / 256, blk, 0, stream>>>(xk, fcos, fsin, HK_, totk);
    }

    attn_kernel<<<dim3((S_/QT) * HQ_ * B_), blk, 0, stream>>>(xq, xk, xv, attn);

    gemm_f32_kernel<<<dim3(D_/GT, M_/GT), blk, 0, stream>>>(attn, wo, out, M_, D_, D_);
}

// Round 3
// 4495.205 us; speedup vs baseline: 1.7120x; 1.7120x over previous
//
#include <hip/hip_runtime.h>
#include <hip/hip_bf16.h>
#include <math.h>

#define B_   2
#define S_   2048
#define D_   4096
#define HQ_  32
#define HK_  8
#define HD_  128
#define REP_ 4
#define M_   (B_*S_)   // 4096 rows of x

typedef __attribute__((ext_vector_type(8))) short bf16x8;
typedef __attribute__((ext_vector_type(4))) short s16x4;
typedef __attribute__((ext_vector_type(4))) float f32x4;

// fp32 -> (hi, lo) bf16 split. hi = rne(v), lo = rne(v - hi).
__device__ __forceinline__ void split2(float v, unsigned short& h, unsigned short& l) {
    __hip_bfloat16 bh = __float2bfloat16(v);
    float fh = __bfloat162float(bh);
    __hip_bfloat16 bl = __float2bfloat16(v - fh);
    h = *reinterpret_cast<unsigned short*>(&bh);
    l = *reinterpret_cast<unsigned short*>(&bl);
}

__device__ __forceinline__ void gload16(void* lds, const void* g) {
    __builtin_amdgcn_global_load_lds(
        (const __attribute__((address_space(1))) unsigned int*)g,
        (__attribute__((address_space(3))) unsigned int*)lds, 16, 0, 0);
}

// ---------------------------------------------------------------------------
// convert_split: fp32 [n] -> hi bf16 [n], lo bf16 [n]   (vectorized by 4)
// ---------------------------------------------------------------------------
__global__ __launch_bounds__(256)
void convert_split_kernel(const float* __restrict__ src,
                          unsigned short* __restrict__ dh,
                          unsigned short* __restrict__ dl, size_t n4) {
    size_t i = (size_t)blockIdx.x * 256 + threadIdx.x;
    if (i >= n4) return;
    float4 v = *reinterpret_cast<const float4*>(&src[i * 4]);
    s16x4 h, l;
    unsigned short hh, ll;
    split2(v.x, hh, ll); h[0] = (short)hh; l[0] = (short)ll;
    split2(v.y, hh, ll); h[1] = (short)hh; l[1] = (short)ll;
    split2(v.z, hh, ll); h[2] = (short)hh; l[2] = (short)ll;
    split2(v.w, hh, ll); h[3] = (short)hh; l[3] = (short)ll;
    *reinterpret_cast<s16x4*>(&dh[i * 4]) = h;
    *reinterpret_cast<s16x4*>(&dl[i * 4]) = l;
}

// ---------------------------------------------------------------------------
// transpose_split: W fp32 [K][N] -> Wt_hi, Wt_lo bf16 [N][K].
// 64x64 tile via LDS. grid = (N/64, K/64), 256 threads.
// ---------------------------------------------------------------------------
__global__ __launch_bounds__(256)
void tsplit_kernel(const float* __restrict__ W,
                   unsigned short* __restrict__ Th,
                   unsigned short* __restrict__ Tl, int K, int N) {
    __shared__ float Ts[64][65];
    const int tid = threadIdx.x;
    const int n0 = blockIdx.x * 64;
    const int k0 = blockIdx.y * 64;
    const int lr = tid >> 4;          // 0..15
    const int lc = (tid & 15) << 2;   // 0,4,..,60
#pragma unroll
    for (int p = 0; p < 4; ++p) {
        int r = p * 16 + lr;          // k offset
        float4 v = *reinterpret_cast<const float4*>(&W[(size_t)(k0 + r) * N + n0 + lc]);
        Ts[r][lc + 0] = v.x; Ts[r][lc + 1] = v.y;
        Ts[r][lc + 2] = v.z; Ts[r][lc + 3] = v.w;
    }
    __syncthreads();
#pragma unroll
    for (int p = 0; p < 4; ++p) {
        int rr = p * 16 + lr;         // n offset
        s16x4 h, l;
#pragma unroll
        for (int i = 0; i < 4; ++i) {
            unsigned short hh, ll;
            split2(Ts[lc + i][rr], hh, ll);
            h[i] = (short)hh; l[i] = (short)ll;
        }
        size_t off = (size_t)(n0 + rr) * K + k0 + lc;
        *reinterpret_cast<s16x4*>(&Th[off]) = h;
        *reinterpret_cast<s16x4*>(&Tl[off]) = l;
    }
}

// ---------------------------------------------------------------------------
// Split-bf16 MFMA GEMM:  C[M][N] (f32) = A[M][K] @ B[K][N]
// A given as (Ah, Al) bf16 [M][K]; B given as (Bth, Btl) bf16 [N][K] (transposed).
// 3-term: Ah*Bh + Ah*Bl + Al*Bh. 128x128 tile, BK=32, 4 waves, 4x4 16x16 frags.
// ---------------------------------------------------------------------------
#define BM 128
#define BN 128
#define BKK 32

__global__ __launch_bounds__(256)
void gemm_split_kernel(const unsigned short* __restrict__ Ah,
                       const unsigned short* __restrict__ Al,
                       const unsigned short* __restrict__ Bh,
                       const unsigned short* __restrict__ Bl,
                       float* __restrict__ C, int M, int N, int K) {
    __shared__ unsigned short lAh[BM * BKK];
    __shared__ unsigned short lAl[BM * BKK];
    __shared__ unsigned short lBh[BN * BKK];
    __shared__ unsigned short lBl[BN * BKK];

    const int tid  = threadIdx.x;
    const int lane = tid & 63;
    const int w    = tid >> 6;           // 0..3
    const int wr   = (w >> 1) * 64;      // wave row offset
    const int wc   = (w & 1) * 64;       // wave col offset
    const int m0   = blockIdx.y * BM;
    const int n0   = blockIdx.x * BN;
    const int l15  = lane & 15;
    const int l4   = lane >> 4;

    f32x4 acc[4][4] = {};

    for (int k0 = 0; k0 < K; k0 += BKK) {
        __syncthreads();   // previous iteration's LDS reads complete
#pragma unroll
        for (int i = 0; i < 2; ++i) {
            int flat = i * 256 + tid;          // 0..511
            int row  = flat >> 2;              // 0..127
            int kc   = (flat & 3) * 8;         // 0,8,16,24
            size_t ga = (size_t)(m0 + row) * K + k0 + kc;
            size_t gb = (size_t)(n0 + row) * K + k0 + kc;
            gload16(&lAh[flat * 8], &Ah[ga]);
            gload16(&lAl[flat * 8], &Al[ga]);
            gload16(&lBh[flat * 8], &Bh[gb]);
            gload16(&lBl[flat * 8], &Bl[gb]);
        }
        __syncthreads();   // drains vmcnt(0): staged data visible

        bf16x8 ah[4], al[4], bh[4], bl[4];
#pragma unroll
        for (int i = 0; i < 4; ++i) {
            ah[i] = *reinterpret_cast<const bf16x8*>(&lAh[(wr + i * 16 + l15) * BKK + l4 * 8]);
            al[i] = *reinterpret_cast<const bf16x8*>(&lAl[(wr + i * 16 + l15) * BKK + l4 * 8]);
            bh[i] = *reinterpret_cast<const bf16x8*>(&lBh[(wc + i * 16 + l15) * BKK + l4 * 8]);
            bl[i] = *reinterpret_cast<const bf16x8*>(&lBl[(wc + i * 16 + l15) * BKK + l4 * 8]);
        }
#pragma unroll
        for (int i = 0; i < 4; ++i)
#pragma unroll
            for (int j = 0; j < 4; ++j) {
                acc[i][j] = __builtin_amdgcn_mfma_f32_16x16x32_bf16(ah[i], bh[j], acc[i][j], 0, 0, 0);
                acc[i][j] = __builtin_amdgcn_mfma_f32_16x16x32_bf16(ah[i], bl[j], acc[i][j], 0, 0, 0);
                acc[i][j] = __builtin_amdgcn_mfma_f32_16x16x32_bf16(al[i], bh[j], acc[i][j], 0, 0, 0);
            }
    }

    // C/D layout (m89-verified): col = lane&15, row = (lane>>4)*4 + reg
#pragma unroll
    for (int i = 0; i < 4; ++i)
#pragma unroll
        for (int j = 0; j < 4; ++j)
#pragma unroll
            for (int r = 0; r < 4; ++r)
                C[(size_t)(m0 + wr + i * 16 + l4 * 4 + r) * N + n0 + wc + j * 16 + l15] =
                    acc[i][j][r];
}

// ---------------------------------------------------------------------------
// RoPE, in place on fp32 [B*S][H*HD].
// ---------------------------------------------------------------------------
__global__ __launch_bounds__(256)
void rope_kernel(float* __restrict__ x, const float* __restrict__ ctab,
                 const float* __restrict__ stab, int H, int total) {
    int idx = blockIdx.x * 256 + threadIdx.x;
    if (idx >= total) return;
    int i  = idx & 63;
    int h  = (idx >> 6) % H;
    int bs = idx / (64 * H);
    int s  = bs & (S_ - 1);
    size_t off = ((size_t)bs * H + h) * HD_ + 2 * i;
    float2 v = *reinterpret_cast<float2*>(&x[off]);
    float c  = ctab[(s << 6) + i];
    float sn = stab[(s << 6) + i];
    float2 o;
    o.x = v.x * c - v.y * sn;
    o.y = v.x * sn + v.y * c;
    *reinterpret_cast<float2*>(&x[off]) = o;
}

// ---------------------------------------------------------------------------
// Flash-style fp32 attention. Writes bf16 hi/lo split output directly.
// Changes vs r2: P stride 65 (softmax loops 8-way -> 2-way conflicts),
// PV d-cols split (tx*4 | 64+tx*4) (V reads 4-way -> 2-way).
// ---------------------------------------------------------------------------
#define QT 64
#define KT 64
#define AP 132
#define PP 65

__global__ __launch_bounds__(256)
void attn_kernel(const float* __restrict__ xq, const float* __restrict__ xk,
                 const float* __restrict__ xv,
                 unsigned short* __restrict__ oh, unsigned short* __restrict__ ol) {
    __shared__ float Qs[QT][AP];
    __shared__ float Ks[KT][AP];
    __shared__ float Vs[KT][AP];
    __shared__ float Ps[QT][PP];
    __shared__ float red[4][QT];
    __shared__ float mrow[QT], lrow[QT], crow[QT];

    const int tid = threadIdx.x;
    const int bid = blockIdx.x;
    const int qb  = bid & 31;
    const int h   = (bid >> 5) & 31;
    const int b   = bid >> 10;
    const int g   = h >> 2;

    const float* Qg = xq + ((size_t)b * S_ + (size_t)qb * QT) * (HQ_ * HD_) + h * HD_;
    const float* Kg = xk + (size_t)b * S_ * (HK_ * HD_) + g * HD_;
    const float* Vg = xv + (size_t)b * S_ * (HK_ * HD_) + g * HD_;

    const int tx = tid & 15;
    const int ty = tid >> 4;

    for (int c = 0; c < 8; ++c) {
        int idx4 = c * 256 + tid;
        int r  = idx4 >> 5;
        int c4 = (idx4 & 31) << 2;
        *reinterpret_cast<float4*>(&Qs[r][c4]) =
            *reinterpret_cast<const float4*>(&Qg[(size_t)r * (HQ_ * HD_) + c4]);
    }
    if (tid < QT) { mrow[tid] = -INFINITY; lrow[tid] = 0.f; }

    float o_acc[4][8];
#pragma unroll
    for (int i = 0; i < 4; ++i)
#pragma unroll
        for (int j = 0; j < 8; ++j) o_acc[i][j] = 0.f;

    const float scale = 0.08838834764831845f;

    for (int kt = 0; kt < S_ / KT; ++kt) {
        __syncthreads();
        const float* Kt_ = Kg + (size_t)kt * KT * (HK_ * HD_);
        const float* Vt_ = Vg + (size_t)kt * KT * (HK_ * HD_);
        for (int c = 0; c < 8; ++c) {
            int idx4 = c * 256 + tid;
            int r  = idx4 >> 5;
            int c4 = (idx4 & 31) << 2;
            *reinterpret_cast<float4*>(&Ks[r][c4]) =
                *reinterpret_cast<const float4*>(&Kt_[(size_t)r * (HK_ * HD_) + c4]);
            *reinterpret_cast<float4*>(&Vs[r][c4]) =
                *reinterpret_cast<const float4*>(&Vt_[(size_t)r * (HK_ * HD_) + c4]);
        }
        __syncthreads();

        // ---- S = Q @ K^T ----
        float sreg[4][4] = {{0.f,0.f,0.f,0.f},{0.f,0.f,0.f,0.f},
                            {0.f,0.f,0.f,0.f},{0.f,0.f,0.f,0.f}};
#pragma unroll 8
        for (int d = 0; d < HD_; d += 4) {
            float4 q[4], k[4];
#pragma unroll
            for (int ii = 0; ii < 4; ++ii)
                q[ii] = *reinterpret_cast<const float4*>(&Qs[ty + 16 * ii][d]);
#pragma unroll
            for (int jj = 0; jj < 4; ++jj)
                k[jj] = *reinterpret_cast<const float4*>(&Ks[tx + 16 * jj][d]);
#pragma unroll
            for (int ii = 0; ii < 4; ++ii)
#pragma unroll
                for (int jj = 0; jj < 4; ++jj)
                    sreg[ii][jj] += q[ii].x * k[jj].x + q[ii].y * k[jj].y +
                                    q[ii].z * k[jj].z + q[ii].w * k[jj].w;
        }
#pragma unroll
        for (int ii = 0; ii < 4; ++ii)
#pragma unroll
            for (int jj = 0; jj < 4; ++jj)
                Ps[ty + 16 * ii][tx + 16 * jj] = sreg[ii][jj] * scale;
        __syncthreads();

        // ---- online softmax ----
        const int row = tid & 63;
        const int p   = tid >> 6;
        float lm = -INFINITY;
        for (int j = 0; j < 16; ++j) lm = fmaxf(lm, Ps[row][p * 16 + j]);
        red[p][row] = lm;
        __syncthreads();
        if (tid < QT) {
            float mt = fmaxf(fmaxf(red[0][tid], red[1][tid]),
                             fmaxf(red[2][tid], red[3][tid]));
            float mo = mrow[tid];
            float mn = fmaxf(mo, mt);
            mrow[tid] = mn;
            crow[tid] = __expf(mo - mn);
        }
        __syncthreads();
        float mn = mrow[row];
        float psum = 0.f;
        for (int j = 0; j < 16; ++j) {
            float e = __expf(Ps[row][p * 16 + j] - mn);
            Ps[row][p * 16 + j] = e;
            psum += e;
        }
        red[p][row] = psum;
        __syncthreads();
        if (tid < QT)
            lrow[tid] = lrow[tid] * crow[tid] +
                        red[0][tid] + red[1][tid] + red[2][tid] + red[3][tid];

        // ---- O = O*corr + P @ V ;  d-cols: [0..3] -> tx*4+dd, [4..7] -> 64+tx*4+dd
        float cr[4];
#pragma unroll
        for (int ii = 0; ii < 4; ++ii) cr[ii] = crow[ty + 16 * ii];
#pragma unroll
        for (int ii = 0; ii < 4; ++ii)
#pragma unroll
            for (int dd = 0; dd < 8; ++dd) o_acc[ii][dd] *= cr[ii];
#pragma unroll 4
        for (int t = 0; t < KT; ++t) {
            float pv[4];
#pragma unroll
            for (int ii = 0; ii < 4; ++ii) pv[ii] = Ps[ty + 16 * ii][t];
            float4 v0 = *reinterpret_cast<const float4*>(&Vs[t][tx * 4]);
            float4 v1 = *reinterpret_cast<const float4*>(&Vs[t][64 + tx * 4]);
            float vv[8] = {v0.x, v0.y, v0.z, v0.w, v1.x, v1.y, v1.z, v1.w};
#pragma unroll
            for (int ii = 0; ii < 4; ++ii)
#pragma unroll
                for (int dd = 0; dd < 8; ++dd) o_acc[ii][dd] += pv[ii] * vv[dd];
        }
    }

    __syncthreads();
#pragma unroll
    for (int ii = 0; ii < 4; ++ii) {
        int r = ty + 16 * ii;
        float inv = 1.f / lrow[r];
        size_t rowg = (size_t)b * S_ + (size_t)qb * QT + r;
        size_t off0 = rowg * (HQ_ * HD_) + h * HD_ + tx * 4;
        size_t off1 = off0 + 64;
        s16x4 h0, l0, h1, l1;
#pragma unroll
        for (int dd = 0; dd < 4; ++dd) {
            unsigned short hh, ll;
            split2(o_acc[ii][dd] * inv, hh, ll);
            h0[dd] = (short)hh; l0[dd] = (short)ll;
            split2(o_acc[ii][4 + dd] * inv, hh, ll);
            h1[dd] = (short)hh; l1[dd] = (short)ll;
        }
        *reinterpret_cast<s16x4*>(&oh[off0]) = h0;
        *reinterpret_cast<s16x4*>(&ol[off0]) = l0;
        *reinterpret_cast<s16x4*>(&oh[off1]) = h1;
        *reinterpret_cast<s16x4*>(&ol[off1]) = l1;
    }
}

// ---------------------------------------------------------------------------
extern "C" void kernel_launch(void* const* d_in, const int* in_sizes, int n_in,
                              void* d_out, int out_size, void* d_ws, size_t ws_size,
                              hipStream_t stream) {
    const float* x    = (const float*)d_in[0];
    const float* wq   = (const float*)d_in[1];
    const float* wk   = (const float*)d_in[2];
    const float* wv   = (const float*)d_in[3];
    const float* wo   = (const float*)d_in[4];
    const float* fcos = (const float*)d_in[5];
    const float* fsin = (const float*)d_in[6];
    float* out = (float*)d_out;

    // workspace layout (268.5 MB total)
    char* p = (char*)d_ws;
    float* xq = (float*)p;            p += (size_t)M_ * 4096 * 4;   // 67.1 MB
    float* xk = (float*)p;            p += (size_t)M_ * 1024 * 4;   // 16.8 MB
    float* xv = (float*)p;            p += (size_t)M_ * 1024 * 4;   // 16.8 MB
    unsigned short* xh = (unsigned short*)p;  p += (size_t)M_ * 4096 * 2;  // x_hi, later attn_hi
    unsigned short* xl = (unsigned short*)p;  p += (size_t)M_ * 4096 * 2;  // x_lo, later attn_lo
    unsigned short* wqt_h = (unsigned short*)p; p += (size_t)4096 * 4096 * 2;  // later wo_t
    unsigned short* wqt_l = (unsigned short*)p; p += (size_t)4096 * 4096 * 2;
    unsigned short* wkt_h = (unsigned short*)p; p += (size_t)1024 * 4096 * 2;
    unsigned short* wkt_l = (unsigned short*)p; p += (size_t)1024 * 4096 * 2;
    unsigned short* wvt_h = (unsigned short*)p; p += (size_t)1024 * 4096 * 2;
    unsigned short* wvt_l = (unsigned short*)p; p += (size_t)1024 * 4096 * 2;

    dim3 blk(256);

    // 1) split x
    {
        size_t n4 = (size_t)M_ * 4096 / 4;
        convert_split_kernel<<<dim3((n4 + 255) / 256), blk, 0, stream>>>(x, xh, xl, n4);
    }
    // 2) transpose+split weights (wq, wk, wv)
    tsplit_kernel<<<dim3(4096 / 64, 4096 / 64), blk, 0, stream>>>(wq, wqt_h, wqt_l, 4096, 4096);
    tsplit_kernel<<<dim3(1024 / 64, 4096 / 64), blk, 0, stream>>>(wk, wkt_h, wkt_l, 4096, 1024);
    tsplit_kernel<<<dim3(1024 / 64, 4096 / 64), blk, 0, stream>>>(wv, wvt_h, wvt_l, 4096, 1024);

    // 3) QKV projections (split-bf16 MFMA)
    gemm_split_kernel<<<dim3(4096 / BN, M_ / BM), blk, 0, stream>>>(xh, xl, wqt_h, wqt_l, xq, M_, 4096, 4096);
    gemm_split_kernel<<<dim3(1024 / BN, M_ / BM), blk, 0, stream>>>(xh, xl, wkt_h, wkt_l, xk, M_, 1024, 4096);
    gemm_split_kernel<<<dim3(1024 / BN, M_ / BM), blk, 0, stream>>>(xh, xl, wvt_h, wvt_l, xv, M_, 1024, 4096);

    // 4) RoPE (fp32, in place)
    {
        int totq = B_ * S_ * HQ_ * (HD_ / 2);
        int totk = B_ * S_ * HK_ * (HD_ / 2);
        rope_kernel<<<(totq + 255) / 256, blk, 0, stream>>>(xq, fcos, fsin, HQ_, totq);
        rope_kernel<<<(totk + 255) / 256, blk, 0, stream>>>(xk, fcos, fsin, HK_, totk);
    }

    // 5) attention -> writes split bf16 into xh/xl (x splits dead now)
    attn_kernel<<<dim3((S_ / QT) * HQ_ * B_), blk, 0, stream>>>(xq, xk, xv, xh, xl);

    // 6) transpose+split wo into wq_t buffers (dead after step 3)
    tsplit_kernel<<<dim3(4096 / 64, 4096 / 64), blk, 0, stream>>>(wo, wqt_h, wqt_l, 4096, 4096);

    // 7) output projection
    gemm_split_kernel<<<dim3(4096 / BN, M_ / BM), blk, 0, stream>>>(xh, xl, wqt_h, wqt_l, out, M_, 4096, 4096);
}

// Round 5
// 2555.856 us; speedup vs baseline: 3.0110x; 1.7588x over previous
//
#include <hip/hip_runtime.h>
#include <hip/hip_bf16.h>
#include <math.h>

#define B_   2
#define S_   2048
#define D_   4096
#define HQ_  32
#define HK_  8
#define HD_  128
#define REP_ 4
#define M_   (B_*S_)   // 4096 rows of x

typedef __attribute__((ext_vector_type(8))) short bf16x8;
typedef __attribute__((ext_vector_type(4))) short s16x4;
typedef __attribute__((ext_vector_type(4))) float f32x4;

// fp32 -> (hi, lo) bf16 split. hi = rne(v), lo = rne(v - hi).
__device__ __forceinline__ void split2(float v, unsigned short& h, unsigned short& l) {
    __hip_bfloat16 bh = __float2bfloat16(v);
    float fh = __bfloat162float(bh);
    __hip_bfloat16 bl = __float2bfloat16(v - fh);
    h = *reinterpret_cast<unsigned short*>(&bh);
    l = *reinterpret_cast<unsigned short*>(&bl);
}

__device__ __forceinline__ void gload16(void* lds, const void* g) {
    __builtin_amdgcn_global_load_lds(
        (const __attribute__((address_space(1))) unsigned int*)g,
        (__attribute__((address_space(3))) unsigned int*)lds, 16, 0, 0);
}

// ---------------------------------------------------------------------------
// convert_split: fp32 [n] -> hi bf16 [n], lo bf16 [n]   (vectorized by 4)
// ---------------------------------------------------------------------------
__global__ __launch_bounds__(256)
void convert_split_kernel(const float* __restrict__ src,
                          unsigned short* __restrict__ dh,
                          unsigned short* __restrict__ dl, size_t n4) {
    size_t i = (size_t)blockIdx.x * 256 + threadIdx.x;
    if (i >= n4) return;
    float4 v = *reinterpret_cast<const float4*>(&src[i * 4]);
    s16x4 h, l;
    unsigned short hh, ll;
    split2(v.x, hh, ll); h[0] = (short)hh; l[0] = (short)ll;
    split2(v.y, hh, ll); h[1] = (short)hh; l[1] = (short)ll;
    split2(v.z, hh, ll); h[2] = (short)hh; l[2] = (short)ll;
    split2(v.w, hh, ll); h[3] = (short)hh; l[3] = (short)ll;
    *reinterpret_cast<s16x4*>(&dh[i * 4]) = h;
    *reinterpret_cast<s16x4*>(&dl[i * 4]) = l;
}

// ---------------------------------------------------------------------------
// transpose_split: W fp32 [K][N] -> Wt_hi, Wt_lo bf16 [N][K].
// ---------------------------------------------------------------------------
__global__ __launch_bounds__(256)
void tsplit_kernel(const float* __restrict__ W,
                   unsigned short* __restrict__ Th,
                   unsigned short* __restrict__ Tl, int K, int N) {
    __shared__ float Ts[64][65];
    const int tid = threadIdx.x;
    const int n0 = blockIdx.x * 64;
    const int k0 = blockIdx.y * 64;
    const int lr = tid >> 4;
    const int lc = (tid & 15) << 2;
#pragma unroll
    for (int p = 0; p < 4; ++p) {
        int r = p * 16 + lr;
        float4 v = *reinterpret_cast<const float4*>(&W[(size_t)(k0 + r) * N + n0 + lc]);
        Ts[r][lc + 0] = v.x; Ts[r][lc + 1] = v.y;
        Ts[r][lc + 2] = v.z; Ts[r][lc + 3] = v.w;
    }
    __syncthreads();
#pragma unroll
    for (int p = 0; p < 4; ++p) {
        int rr = p * 16 + lr;
        s16x4 h, l;
#pragma unroll
        for (int i = 0; i < 4; ++i) {
            unsigned short hh, ll;
            split2(Ts[lc + i][rr], hh, ll);
            h[i] = (short)hh; l[i] = (short)ll;
        }
        size_t off = (size_t)(n0 + rr) * K + k0 + lc;
        *reinterpret_cast<s16x4*>(&Th[off]) = h;
        *reinterpret_cast<s16x4*>(&Tl[off]) = l;
    }
}

// ---------------------------------------------------------------------------
// Split-bf16 MFMA GEMM (unchanged, passing).
// ---------------------------------------------------------------------------
#define BM 128
#define BN 128
#define BKK 32

__global__ __launch_bounds__(256)
void gemm_split_kernel(const unsigned short* __restrict__ Ah,
                       const unsigned short* __restrict__ Al,
                       const unsigned short* __restrict__ Bh,
                       const unsigned short* __restrict__ Bl,
                       float* __restrict__ C, int M, int N, int K) {
    __shared__ unsigned short lAh[BM * BKK];
    __shared__ unsigned short lAl[BM * BKK];
    __shared__ unsigned short lBh[BN * BKK];
    __shared__ unsigned short lBl[BN * BKK];

    const int tid  = threadIdx.x;
    const int lane = tid & 63;
    const int w    = tid >> 6;
    const int wr   = (w >> 1) * 64;
    const int wc   = (w & 1) * 64;
    const int m0   = blockIdx.y * BM;
    const int n0   = blockIdx.x * BN;
    const int l15  = lane & 15;
    const int l4   = lane >> 4;

    f32x4 acc[4][4] = {};

    for (int k0 = 0; k0 < K; k0 += BKK) {
        __syncthreads();
#pragma unroll
        for (int i = 0; i < 2; ++i) {
            int flat = i * 256 + tid;
            int row  = flat >> 2;
            int kc   = (flat & 3) * 8;
            size_t ga = (size_t)(m0 + row) * K + k0 + kc;
            size_t gb = (size_t)(n0 + row) * K + k0 + kc;
            gload16(&lAh[flat * 8], &Ah[ga]);
            gload16(&lAl[flat * 8], &Al[ga]);
            gload16(&lBh[flat * 8], &Bh[gb]);
            gload16(&lBl[flat * 8], &Bl[gb]);
        }
        __syncthreads();

        bf16x8 ah[4], al[4], bh[4], bl[4];
#pragma unroll
        for (int i = 0; i < 4; ++i) {
            ah[i] = *reinterpret_cast<const bf16x8*>(&lAh[(wr + i * 16 + l15) * BKK + l4 * 8]);
            al[i] = *reinterpret_cast<const bf16x8*>(&lAl[(wr + i * 16 + l15) * BKK + l4 * 8]);
            bh[i] = *reinterpret_cast<const bf16x8*>(&lBh[(wc + i * 16 + l15) * BKK + l4 * 8]);
            bl[i] = *reinterpret_cast<const bf16x8*>(&lBl[(wc + i * 16 + l15) * BKK + l4 * 8]);
        }
#pragma unroll
        for (int i = 0; i < 4; ++i)
#pragma unroll
            for (int j = 0; j < 4; ++j) {
                acc[i][j] = __builtin_amdgcn_mfma_f32_16x16x32_bf16(ah[i], bh[j], acc[i][j], 0, 0, 0);
                acc[i][j] = __builtin_amdgcn_mfma_f32_16x16x32_bf16(ah[i], bl[j], acc[i][j], 0, 0, 0);
                acc[i][j] = __builtin_amdgcn_mfma_f32_16x16x32_bf16(al[i], bh[j], acc[i][j], 0, 0, 0);
            }
    }
#pragma unroll
    for (int i = 0; i < 4; ++i)
#pragma unroll
        for (int j = 0; j < 4; ++j)
#pragma unroll
            for (int r = 0; r < 4; ++r)
                C[(size_t)(m0 + wr + i * 16 + l4 * 4 + r) * N + n0 + wc + j * 16 + l15] =
                    acc[i][j][r];
}

// ---------------------------------------------------------------------------
// RoPE + hi/lo split: fp32 [b,s,H,128] -> Qh/Ql (same layout, bf16 as ushort)
// ---------------------------------------------------------------------------
__global__ __launch_bounds__(256)
void rope_split_kernel(const float* __restrict__ xin, const float* __restrict__ ctab,
                       const float* __restrict__ stab,
                       unsigned short* __restrict__ dh, unsigned short* __restrict__ dl,
                       int H, int total) {
    int idx = blockIdx.x * 256 + threadIdx.x;
    if (idx >= total) return;
    int i  = idx & 63;
    int h  = (idx >> 6) % H;
    int bs = idx / (64 * H);
    int s  = bs & (S_ - 1);
    size_t off = ((size_t)bs * H + h) * HD_ + 2 * i;
    float2 v = *reinterpret_cast<const float2*>(&xin[off]);
    float c  = ctab[(s << 6) + i];
    float sn = stab[(s << 6) + i];
    float o0 = v.x * c - v.y * sn;
    float o1 = v.x * sn + v.y * c;
    unsigned short h0, l0, h1, l1;
    split2(o0, h0, l0);
    split2(o1, h1, l1);
    ushort2 hh; hh.x = h0; hh.y = h1;
    ushort2 ll; ll.x = l0; ll.y = l1;
    *reinterpret_cast<ushort2*>(&dh[off]) = hh;
    *reinterpret_cast<ushort2*>(&dl[off]) = ll;
}

// ---------------------------------------------------------------------------
// V transpose+split: xv fp32 [b, s, g, d] -> Vt hi/lo bf16 [b, g, d, S]
// grid (S/64, HD/64, B*HK)
// ---------------------------------------------------------------------------
__global__ __launch_bounds__(256)
void vsplit_t_kernel(const float* __restrict__ xv,
                     unsigned short* __restrict__ th, unsigned short* __restrict__ tl) {
    __shared__ float Ts[64][65];
    const int tid = threadIdx.x;
    const int s0 = blockIdx.x * 64;
    const int d0 = blockIdx.y * 64;
    const int bg = blockIdx.z;           // b*8 + g
    const int b  = bg >> 3;
    const int g  = bg & 7;
    const int lr = tid >> 4;
    const int lc = (tid & 15) << 2;
#pragma unroll
    for (int p = 0; p < 4; ++p) {
        int r = p * 16 + lr;             // s offset
        float4 v = *reinterpret_cast<const float4*>(
            &xv[(size_t)(b * S_ + s0 + r) * (HK_ * HD_) + g * HD_ + d0 + lc]);
        Ts[r][lc + 0] = v.x; Ts[r][lc + 1] = v.y;
        Ts[r][lc + 2] = v.z; Ts[r][lc + 3] = v.w;
    }
    __syncthreads();
#pragma unroll
    for (int p = 0; p < 4; ++p) {
        int rr = p * 16 + lr;            // d offset
        s16x4 h, l;
#pragma unroll
        for (int i = 0; i < 4; ++i) {
            unsigned short hh, ll;
            split2(Ts[lc + i][rr], hh, ll);
            h[i] = (short)hh; l[i] = (short)ll;
        }
        size_t off = ((size_t)bg * HD_ + d0 + rr) * S_ + s0 + lc;
        *reinterpret_cast<s16x4*>(&th[off]) = h;
        *reinterpret_cast<s16x4*>(&tl[off]) = l;
    }
}

// ---------------------------------------------------------------------------
// MFMA flash attention, split-bf16 3-term everywhere.
// 512 threads = 8 waves; Q-tile 256 (32 q/wave), K/V tiles 64.
// LDS strides: K 136 ushorts, V/P 72 ushorts (conflict-checked).
// ---------------------------------------------------------------------------
__global__ __launch_bounds__(512)
void attn_mfma_kernel(const unsigned short* __restrict__ Qh, const unsigned short* __restrict__ Ql,
                      const unsigned short* __restrict__ Kh, const unsigned short* __restrict__ Kl,
                      const unsigned short* __restrict__ Vh, const unsigned short* __restrict__ Vl,
                      unsigned short* __restrict__ oh, unsigned short* __restrict__ ol) {
    __shared__ unsigned short smem[72704];    // 145408 B
    unsigned short* KsH = smem;               // 64 x 136
    unsigned short* KsL = smem + 8704;
    unsigned short* VsH = smem + 17408;       // 128 x 72
    unsigned short* VsL = smem + 26624;
    unsigned short* Ph  = smem + 35840;       // 256 x 72
    unsigned short* Pl  = smem + 54272;
    unsigned short* Qst = smem + 35840;       // 256 x 136 staging (overlaps Ph/Pl)

    const int tid  = threadIdx.x;
    const int lane = tid & 63;
    const int w    = tid >> 6;
    const int l15  = lane & 15;
    const int l4   = lane >> 4;

    // XCD-chunked swizzle: 512 = 8 XCD x 64 chunks
    const int lbid = ((blockIdx.x & 7) << 6) | (blockIdx.x >> 3);
    const int qb   = lbid & 7;
    const int rep  = (lbid >> 3) & 3;
    const int g    = (lbid >> 5) & 7;
    const int b    = lbid >> 8;
    const int h    = g * REP_ + rep;

    const size_t qrow0 = (size_t)b * S_ + (size_t)qb * 256;

    // ---- prologue: Q A-frags into registers (via LDS staging) ----
    bf16x8 qf_h[2][4], qf_l[2][4];
#pragma unroll
    for (int half = 0; half < 2; ++half) {
        const unsigned short* src = half ? Ql : Qh;
#pragma unroll
        for (int t = 0; t < 8; ++t) {
            int flat = t * 512 + tid;
            int r = flat >> 4, c = flat & 15;
            *reinterpret_cast<bf16x8*>(&Qst[r * 136 + c * 8]) =
                *reinterpret_cast<const bf16x8*>(&src[(qrow0 + r) * (HQ_ * HD_) + h * HD_ + c * 8]);
        }
        __syncthreads();
#pragma unroll
        for (int mf = 0; mf < 2; ++mf)
#pragma unroll
            for (int ks = 0; ks < 4; ++ks) {
                bf16x8 v = *reinterpret_cast<const bf16x8*>(
                    &Qst[(w * 32 + mf * 16 + l15) * 136 + ks * 32 + l4 * 8]);
                if (half) qf_l[mf][ks] = v; else qf_h[mf][ks] = v;
            }
        __syncthreads();
    }

    f32x4 o_acc[2][8];
#pragma unroll
    for (int mf = 0; mf < 2; ++mf)
#pragma unroll
        for (int nf = 0; nf < 8; ++nf) o_acc[mf][nf] = (f32x4){0.f, 0.f, 0.f, 0.f};
    float m_[2][4], l_[2][4];
#pragma unroll
    for (int mf = 0; mf < 2; ++mf)
#pragma unroll
        for (int r = 0; r < 4; ++r) { m_[mf][r] = -INFINITY; l_[mf][r] = 0.f; }

    const float scale = 0.08838834764831845f;   // 1/sqrt(128)

    for (int kt = 0; kt < S_ / 64; ++kt) {
        const int kv0 = kt * 64;
        // ---- stage K (64x128) and V^T (128x64), hi/lo ----
#pragma unroll
        for (int t = 0; t < 2; ++t) {
            int flat = t * 512 + tid;
            int r = flat >> 4, c = flat & 15;
            size_t gk = (size_t)(b * S_ + kv0 + r) * (HK_ * HD_) + g * HD_ + c * 8;
            *reinterpret_cast<bf16x8*>(&KsH[r * 136 + c * 8]) =
                *reinterpret_cast<const bf16x8*>(&Kh[gk]);
            *reinterpret_cast<bf16x8*>(&KsL[r * 136 + c * 8]) =
                *reinterpret_cast<const bf16x8*>(&Kl[gk]);
            int rv = flat >> 3, cv = flat & 7;
            size_t gv = ((size_t)(b * HK_ + g) * HD_ + rv) * S_ + kv0 + cv * 8;
            *reinterpret_cast<bf16x8*>(&VsH[rv * 72 + cv * 8]) =
                *reinterpret_cast<const bf16x8*>(&Vh[gv]);
            *reinterpret_cast<bf16x8*>(&VsL[rv * 72 + cv * 8]) =
                *reinterpret_cast<const bf16x8*>(&Vl[gv]);
        }
        __syncthreads();

        // ---- S = Q K^T (split 3-term) ----
        f32x4 s_acc[2][4];
#pragma unroll
        for (int mf = 0; mf < 2; ++mf)
#pragma unroll
            for (int nf = 0; nf < 4; ++nf) s_acc[mf][nf] = (f32x4){0.f, 0.f, 0.f, 0.f};
#pragma unroll
        for (int ks = 0; ks < 4; ++ks) {
            bf16x8 kfh[4], kfl[4];
#pragma unroll
            for (int nf = 0; nf < 4; ++nf) {
                kfh[nf] = *reinterpret_cast<const bf16x8*>(
                    &KsH[(nf * 16 + l15) * 136 + ks * 32 + l4 * 8]);
                kfl[nf] = *reinterpret_cast<const bf16x8*>(
                    &KsL[(nf * 16 + l15) * 136 + ks * 32 + l4 * 8]);
            }
#pragma unroll
            for (int mf = 0; mf < 2; ++mf)
#pragma unroll
                for (int nf = 0; nf < 4; ++nf) {
                    s_acc[mf][nf] = __builtin_amdgcn_mfma_f32_16x16x32_bf16(qf_h[mf][ks], kfh[nf], s_acc[mf][nf], 0, 0, 0);
                    s_acc[mf][nf] = __builtin_amdgcn_mfma_f32_16x16x32_bf16(qf_h[mf][ks], kfl[nf], s_acc[mf][nf], 0, 0, 0);
                    s_acc[mf][nf] = __builtin_amdgcn_mfma_f32_16x16x32_bf16(qf_l[mf][ks], kfh[nf], s_acc[mf][nf], 0, 0, 0);
                }
        }

        // ---- online softmax (rows = l4*4+r per m-frag; reduce over l15 lanes) ----
        float mx[2][4];
#pragma unroll
        for (int mf = 0; mf < 2; ++mf)
#pragma unroll
            for (int r = 0; r < 4; ++r) {
                float v = s_acc[mf][0][r];
                v = fmaxf(v, s_acc[mf][1][r]);
                v = fmaxf(v, s_acc[mf][2][r]);
                v = fmaxf(v, s_acc[mf][3][r]);
                mx[mf][r] = v * scale;
            }
#pragma unroll
        for (int mask = 1; mask < 16; mask <<= 1)
#pragma unroll
            for (int mf = 0; mf < 2; ++mf)
#pragma unroll
                for (int r = 0; r < 4; ++r)
                    mx[mf][r] = fmaxf(mx[mf][r], __shfl_xor(mx[mf][r], mask));
        float c_[2][4];
#pragma unroll
        for (int mf = 0; mf < 2; ++mf)
#pragma unroll
            for (int r = 0; r < 4; ++r) {
                float mn = fmaxf(m_[mf][r], mx[mf][r]);
                c_[mf][r] = __expf(m_[mf][r] - mn);
                m_[mf][r] = mn;
            }
        // P = exp(S*scale - m); write split to LDS; accumulate row sums
        float sm[2][4];
#pragma unroll
        for (int mf = 0; mf < 2; ++mf)
#pragma unroll
            for (int r = 0; r < 4; ++r) sm[mf][r] = 0.f;
#pragma unroll
        for (int mf = 0; mf < 2; ++mf)
#pragma unroll
            for (int nf = 0; nf < 4; ++nf) {
                int q  = w * 32 + mf * 16 + l4 * 4;
                int kv = nf * 16 + l15;
#pragma unroll
                for (int r = 0; r < 4; ++r) {
                    float p = __expf(s_acc[mf][nf][r] * scale - m_[mf][r]);
                    sm[mf][r] += p;
                    unsigned short hh, ll;
                    split2(p, hh, ll);
                    Ph[(q + r) * 72 + kv] = hh;
                    Pl[(q + r) * 72 + kv] = ll;
                }
            }
#pragma unroll
        for (int mask = 1; mask < 16; mask <<= 1)
#pragma unroll
            for (int mf = 0; mf < 2; ++mf)
#pragma unroll
                for (int r = 0; r < 4; ++r)
                    sm[mf][r] += __shfl_xor(sm[mf][r], mask);
#pragma unroll
        for (int mf = 0; mf < 2; ++mf)
#pragma unroll
            for (int r = 0; r < 4; ++r)
                l_[mf][r] = l_[mf][r] * c_[mf][r] + sm[mf][r];
        // rescale O
#pragma unroll
        for (int mf = 0; mf < 2; ++mf)
#pragma unroll
            for (int nf = 0; nf < 8; ++nf)
#pragma unroll
                for (int r = 0; r < 4; ++r)
                    o_acc[mf][nf][r] *= c_[mf][r];
        __syncthreads();   // P visible

        // ---- O += P V (split 3-term) ----
#pragma unroll
        for (int ks2 = 0; ks2 < 2; ++ks2) {
            bf16x8 pah[2], pal[2];
#pragma unroll
            for (int mf = 0; mf < 2; ++mf) {
                pah[mf] = *reinterpret_cast<const bf16x8*>(
                    &Ph[(w * 32 + mf * 16 + l15) * 72 + ks2 * 32 + l4 * 8]);
                pal[mf] = *reinterpret_cast<const bf16x8*>(
                    &Pl[(w * 32 + mf * 16 + l15) * 72 + ks2 * 32 + l4 * 8]);
            }
#pragma unroll
            for (int nf = 0; nf < 8; ++nf) {
                bf16x8 vfh = *reinterpret_cast<const bf16x8*>(
                    &VsH[(nf * 16 + l15) * 72 + ks2 * 32 + l4 * 8]);
                bf16x8 vfl = *reinterpret_cast<const bf16x8*>(
                    &VsL[(nf * 16 + l15) * 72 + ks2 * 32 + l4 * 8]);
#pragma unroll
                for (int mf = 0; mf < 2; ++mf) {
                    o_acc[mf][nf] = __builtin_amdgcn_mfma_f32_16x16x32_bf16(pah[mf], vfh, o_acc[mf][nf], 0, 0, 0);
                    o_acc[mf][nf] = __builtin_amdgcn_mfma_f32_16x16x32_bf16(pah[mf], vfl, o_acc[mf][nf], 0, 0, 0);
                    o_acc[mf][nf] = __builtin_amdgcn_mfma_f32_16x16x32_bf16(pal[mf], vfh, o_acc[mf][nf], 0, 0, 0);
                }
            }
        }
        __syncthreads();   // all reads done before next stage
    }

    // ---- epilogue: O / l -> split bf16, layout [b,s,h,d] ----
    float inv[2][4];
#pragma unroll
    for (int mf = 0; mf < 2; ++mf)
#pragma unroll
        for (int r = 0; r < 4; ++r) inv[mf][r] = 1.f / l_[mf][r];
#pragma unroll
    for (int mf = 0; mf < 2; ++mf)
#pragma unroll
        for (int nf = 0; nf < 8; ++nf) {
            int d = nf * 16 + l15;
#pragma unroll
            for (int r = 0; r < 4; ++r) {
                int q = w * 32 + mf * 16 + l4 * 4 + r;
                float val = o_acc[mf][nf][r] * inv[mf][r];
                unsigned short hh, ll;
                split2(val, hh, ll);
                size_t off = (qrow0 + q) * (HQ_ * HD_) + h * HD_ + d;
                oh[off] = hh;
                ol[off] = ll;
            }
        }
}

// ---------------------------------------------------------------------------
extern "C" void kernel_launch(void* const* d_in, const int* in_sizes, int n_in,
                              void* d_out, int out_size, void* d_ws, size_t ws_size,
                              hipStream_t stream) {
    const float* x    = (const float*)d_in[0];
    const float* wq   = (const float*)d_in[1];
    const float* wk   = (const float*)d_in[2];
    const float* wv   = (const float*)d_in[3];
    const float* wo   = (const float*)d_in[4];
    const float* fcos = (const float*)d_in[5];
    const float* fsin = (const float*)d_in[6];
    float* out = (float*)d_out;

    // workspace layout (268.5 MB)
    char* p = (char*)d_ws;
    float* xq = (float*)p;            p += (size_t)M_ * 4096 * 4;   // fp32 q; later oh/ol
    float* xk = (float*)p;            p += (size_t)M_ * 1024 * 4;
    float* xv = (float*)p;            p += (size_t)M_ * 1024 * 4;
    unsigned short* xh = (unsigned short*)p;  p += (size_t)M_ * 4096 * 2;  // x_hi -> Qh
    unsigned short* xl = (unsigned short*)p;  p += (size_t)M_ * 4096 * 2;  // x_lo -> Ql
    unsigned short* wqt_h = (unsigned short*)p; p += (size_t)4096 * 4096 * 2;  // later wo_t
    unsigned short* wqt_l = (unsigned short*)p; p += (size_t)4096 * 4096 * 2;
    unsigned short* wkt_h = (unsigned short*)p; p += (size_t)1024 * 4096 * 2;  // later Kh
    unsigned short* wkt_l = (unsigned short*)p; p += (size_t)1024 * 4096 * 2;  // later Kl
    unsigned short* wvt_h = (unsigned short*)p; p += (size_t)1024 * 4096 * 2;  // later Vth
    unsigned short* wvt_l = (unsigned short*)p; p += (size_t)1024 * 4096 * 2;  // later Vtl

    unsigned short* Kh  = wkt_h;
    unsigned short* Kl  = wkt_l;
    unsigned short* Vth = wvt_h;
    unsigned short* Vtl = wvt_l;
    unsigned short* oh  = (unsigned short*)xq;
    unsigned short* ol  = oh + (size_t)M_ * 4096;

    dim3 blk(256);

    // 1) split x
    {
        size_t n4 = (size_t)M_ * 4096 / 4;
        convert_split_kernel<<<dim3((n4 + 255) / 256), blk, 0, stream>>>(x, xh, xl, n4);
    }
    // 2) transpose+split weights
    tsplit_kernel<<<dim3(4096 / 64, 4096 / 64), blk, 0, stream>>>(wq, wqt_h, wqt_l, 4096, 4096);
    tsplit_kernel<<<dim3(1024 / 64, 4096 / 64), blk, 0, stream>>>(wk, wkt_h, wkt_l, 4096, 1024);
    tsplit_kernel<<<dim3(1024 / 64, 4096 / 64), blk, 0, stream>>>(wv, wvt_h, wvt_l, 4096, 1024);

    // 3) QKV projections (fp32 out)
    gemm_split_kernel<<<dim3(4096 / BN, M_ / BM), blk, 0, stream>>>(xh, xl, wqt_h, wqt_l, xq, M_, 4096, 4096);
    gemm_split_kernel<<<dim3(1024 / BN, M_ / BM), blk, 0, stream>>>(xh, xl, wkt_h, wkt_l, xk, M_, 1024, 4096);
    gemm_split_kernel<<<dim3(1024 / BN, M_ / BM), blk, 0, stream>>>(xh, xl, wvt_h, wvt_l, xv, M_, 1024, 4096);

    // 4) RoPE + split:  xq -> (xh,xl) as Qh/Ql;  xk -> (Kh,Kl)  [wkt dead]
    {
        int totq = B_ * S_ * HQ_ * (HD_ / 2);
        int totk = B_ * S_ * HK_ * (HD_ / 2);
        rope_split_kernel<<<(totq + 255) / 256, blk, 0, stream>>>(xq, fcos, fsin, xh, xl, HQ_, totq);
        rope_split_kernel<<<(totk + 255) / 256, blk, 0, stream>>>(xk, fcos, fsin, Kh, Kl, HK_, totk);
    }
    // 5) V transpose+split  [wvt dead]
    vsplit_t_kernel<<<dim3(S_ / 64, HD_ / 64, B_ * HK_), blk, 0, stream>>>(xv, Vth, Vtl);

    // 6) MFMA attention -> oh/ol (xq fp32 dead)
    attn_mfma_kernel<<<dim3(512), dim3(512), 0, stream>>>(xh, xl, Kh, Kl, Vth, Vtl, oh, ol);

    // 7) wo transpose+split into wqt (dead) + output projection
    tsplit_kernel<<<dim3(4096 / 64, 4096 / 64), blk, 0, stream>>>(wo, wqt_h, wqt_l, 4096, 4096);
    gemm_split_kernel<<<dim3(4096 / BN, M_ / BM), blk, 0, stream>>>(oh, ol, wqt_h, wqt_l, out, M_, 4096, 4096);
}